// Round 1
// baseline (62.824 us; speedup 1.0000x reference)
//
#include <hip/hip_runtime.h>

#define NB 32
#define NA 3
#define NT 30
#define NCLS 80
#define NPT (3 * NB * NT)   // 2880 (scale, b, t) triples

__device__ inline void atomicAddD(double* addr, double val) {
    unsigned long long* a = (unsigned long long*)addr;
    unsigned long long old = *a, assumed;
    do {
        assumed = old;
        double nv = __longlong_as_double(assumed) + val;
        old = atomicCAS(a, assumed, __double_as_longlong(nv));
    } while (old != assumed);
}

__global__ __launch_bounds__(1024) void yolo_loss_kernel(
    const float* __restrict__ o0, const float* __restrict__ o1, const float* __restrict__ o2,
    const float* __restrict__ a0, const float* __restrict__ a1, const float* __restrict__ a2,
    const float* __restrict__ tg, float* __restrict__ dout)
{
    __shared__ float s_t[NB * NT * 5];     // targets, 19.2 KB
    __shared__ int   s_key[NPT];           // cell keys, 11.5 KB
    __shared__ float s_anc[3][NA][2];
    __shared__ double s_sq[3], s_bce[3];
    __shared__ int    s_cnt[3];

    const int tid = threadIdx.x;
    const int nth = blockDim.x;

    if (tid < 3) { s_sq[tid] = 0.0; s_bce[tid] = 0.0; s_cnt[tid] = 0; }
    if (tid < 18) {
        int s = tid / 6, j = tid % 6;
        const float* ap = (s == 0) ? a0 : (s == 1) ? a1 : a2;
        s_anc[s][j / 2][j % 2] = ap[j];
    }
    for (int i = tid; i < NB * NT * 5; i += nth) s_t[i] = tg[i];
    __syncthreads();

    // ---- Phase 1: per-(scale,b,t) cell key = ((b*NA+best)*g+gi)*g+gj ----
    for (int i = tid; i < NPT; i += nth) {
        int s = i / (NB * NT), r = i % (NB * NT), b = r / NT, t = r % NT;
        int g = 13 << s;                        // 13, 26, 52
        const float* tp = &s_t[(b * NT + t) * 5];
        float gf = (float)g;
        float gx = tp[0] * gf;
        float gy = tp[1] * gf;
        float gw = fabsf(tp[2] - tp[0]) * (416.0f * gf);
        float gh = fabsf(tp[3] - tp[1]) * (416.0f * gf);
        int best = 0; float bestiou = -1.0f;
        for (int a = 0; a < NA; ++a) {
            float aw = s_anc[s][a][0], ah = s_anc[s][a][1];
            float inter = fminf(aw, gw) * fminf(ah, gh);
            float uni = 1e-8f + aw * ah + gw * gh - inter;
            float iou = inter / uni;
            if (iou > bestiou) { bestiou = iou; best = a; }   // first-max wins (jnp.argmax)
        }
        int gi = (int)gx, gj = (int)gy;         // truncation == floor (values >= 0)
        s_key[i] = ((b * NA + best) * g + gi) * g + gj;
    }
    __syncthreads();

    // ---- Phase 2: dedup (last t wins), gather class union bits, accumulate ----
    double l_sq[3]  = {0.0, 0.0, 0.0};
    double l_bce[3] = {0.0, 0.0, 0.0};
    int    l_cnt[3] = {0, 0, 0};

    for (int i = tid; i < NPT; i += nth) {
        int s = i / (NB * NT), r = i % (NB * NT), b = r / NT, t = r % NT;
        int key = s_key[i];
        int kb = s * NB * NT + b * NT;
        unsigned long long bits_lo = 0ull, bits_hi = 0ull;
        bool win = true;
        for (int t2 = 0; t2 < NT; ++t2) {
            if (s_key[kb + t2] == key) {
                if (t2 > t) { win = false; break; }   // a later target overwrites -> lose
                int c = (int)s_t[(b * NT + t2) * 5 + 4];
                if (c < 64) bits_lo |= 1ull << c; else bits_hi |= 1ull << (c - 64);
            }
        }
        if (!win) continue;

        int g = 13 << s;
        float gf = (float)g;
        const float* tp = &s_t[(b * NT + t) * 5];
        float gx = tp[0] * gf;
        float gy = tp[1] * gf;
        float gw = fabsf(tp[2] - tp[0]) * (416.0f * gf);
        float gh = fabsf(tp[3] - tp[1]) * (416.0f * gf);
        int best = (key / (g * g)) % NA;
        float tx = gx - floorf(gx);
        float ty = gy - floorf(gy);
        float tw = logf(gw / s_anc[s][best][0]);
        float th = logf(gh / s_anc[s][best][1]);

        const float* op = (s == 0) ? o0 : (s == 1) ? o1 : o2;
        const float* cell = op + (size_t)key * (5 + NCLS);

        float d0 = cell[0] - tx, d1 = cell[1] - ty, d2 = cell[2] - tw, d3 = cell[3] - th;
        l_sq[s] += (double)d0 * d0 + (double)d1 * d1 + (double)d2 * d2 + (double)d3 * d3;

        double bs = 0.0;
        for (int c = 0; c < NCLS; ++c) {
            float p = cell[5 + c];
            p = fminf(fmaxf(p, 1e-7f), 1.0f - 1e-7f);
            bool one = (c < 64) ? ((bits_lo >> c) & 1ull) : ((bits_hi >> (c - 64)) & 1ull);
            bs += (double)(one ? -logf(p) : -logf(1.0f - p));
        }
        l_bce[s] += bs;
        l_cnt[s] += 1;
    }

    // ---- wave-level shuffle reduce, then one shared-atomic per wave ----
    for (int s = 0; s < 3; ++s) {
        double vsq = l_sq[s], vbce = l_bce[s];
        int vc = l_cnt[s];
        for (int off = 32; off > 0; off >>= 1) {
            vsq  += __shfl_down(vsq, off);
            vbce += __shfl_down(vbce, off);
            vc   += __shfl_down(vc, off);
        }
        if ((tid & 63) == 0) {
            if (vsq != 0.0)  atomicAddD(&s_sq[s], vsq);
            if (vbce != 0.0) atomicAddD(&s_bce[s], vbce);
            if (vc)          atomicAdd(&s_cnt[s], vc);
        }
    }
    __syncthreads();

    if (tid == 0) {
        double loss = 0.0;
        for (int s = 0; s < 3; ++s) {
            double c = (s_cnt[s] > 0) ? (double)s_cnt[s] : 1.0;
            loss += s_sq[s] / c + s_bce[s] / (c * (double)NCLS);
        }
        dout[0] = (float)loss;
    }
}

extern "C" void kernel_launch(void* const* d_in, const int* in_sizes, int n_in,
                              void* d_out, int out_size, void* d_ws, size_t ws_size,
                              hipStream_t stream) {
    const float* o0 = (const float*)d_in[0];
    const float* o1 = (const float*)d_in[1];
    const float* o2 = (const float*)d_in[2];
    const float* a0 = (const float*)d_in[3];
    const float* a1 = (const float*)d_in[4];
    const float* a2 = (const float*)d_in[5];
    const float* tg = (const float*)d_in[6];
    float* out = (float*)d_out;

    hipLaunchKernelGGL(yolo_loss_kernel, dim3(1), dim3(1024), 0, stream,
                       o0, o1, o2, a0, a1, a2, tg, out);
}